// Round 1
// baseline (863.655 us; speedup 1.0000x reference)
//
#include <hip/hip_runtime.h>
#include <hip/hip_bf16.h>

#define GG 64      // B*N graphs
#define LN 2048    // nodes per graph
#define BB 4       // batch
#define NS 16      // sets per batch
#define EE 16384   // edges
#define C_0 64
#define CH 128
#define EPSV 1e-5f

// ---------- graph preprocessing ----------
__global__ void k_deg(const int* __restrict__ dst, int* __restrict__ cnt) {
    int e = blockIdx.x * blockDim.x + threadIdx.x;
    if (e < EE) atomicAdd(&cnt[dst[e]], 1);
}

__global__ void k_node(const int* __restrict__ cnt, float* __restrict__ dinv,
                       float* __restrict__ selfc) {
    int l = blockIdx.x * blockDim.x + threadIdx.x;
    if (l < LN) {
        float d = (float)cnt[l] + 2.0f;   // improved GCN: A + 2I
        float di = rsqrtf(d);
        dinv[l] = di;
        selfc[l] = 2.0f * di * di;
    }
}

__global__ void k_scan(const int* __restrict__ cnt, int* __restrict__ off) {
    __shared__ int part[256];
    __shared__ int pre[256];
    int t = threadIdx.x;
    int base = t * 8;
    int loc[8];
    int s = 0;
#pragma unroll
    for (int i = 0; i < 8; i++) { loc[i] = cnt[base + i]; s += loc[i]; }
    part[t] = s;
    __syncthreads();
    if (t == 0) {
        int run = 0;
        for (int i = 0; i < 256; i++) { pre[i] = run; run += part[i]; }
        off[LN] = run;
    }
    __syncthreads();
    int run = pre[t];
#pragma unroll
    for (int i = 0; i < 8; i++) { off[base + i] = run; run += loc[i]; }
}

__global__ void k_fill(const int* __restrict__ src, const int* __restrict__ dst,
                       const int* __restrict__ off, int* __restrict__ cur,
                       const float* __restrict__ dinv,
                       int* __restrict__ ssrc, float* __restrict__ snorm) {
    int e = blockIdx.x * blockDim.x + threadIdx.x;
    if (e < EE) {
        int s = src[e], d = dst[e];
        int pos = atomicAdd(&cur[d], 1);
        int idx = off[d] + pos;
        ssrc[idx] = s;
        snorm[idx] = dinv[s] * dinv[d];
    }
}

// ---------- GEMM: out[g,l,co] = sum_k A[g,l,k] * W[k,co] ----------
// AT=true: A is x in [G, K, L] layout (layer 1 reads x directly, transposed load)
template <int K, bool AT>
__global__ __launch_bounds__(256) void k_mm(const float* __restrict__ A,
                                            const float* __restrict__ W,
                                            float* __restrict__ out) {
    __shared__ float As[64][33];
    __shared__ float Bs[32][128];
    int g = blockIdx.y;
    int l0 = blockIdx.x * 64;
    int t = threadIdx.x;
    int rg = t >> 4, cg = t & 15;
    float acc[4][8];
#pragma unroll
    for (int i = 0; i < 4; i++)
#pragma unroll
        for (int j = 0; j < 8; j++) acc[i][j] = 0.f;

    for (int k0 = 0; k0 < K; k0 += 32) {
        if (AT) {
#pragma unroll
            for (int p = 0; p < 2; p++) {
                int q = t + 256 * p;
                int kk = q >> 4;
                int l4 = (q & 15) * 4;
                float4 v = *reinterpret_cast<const float4*>(
                    &A[((size_t)g * K + k0 + kk) * LN + l0 + l4]);
                As[l4 + 0][kk] = v.x; As[l4 + 1][kk] = v.y;
                As[l4 + 2][kk] = v.z; As[l4 + 3][kk] = v.w;
            }
        } else {
#pragma unroll
            for (int p = 0; p < 2; p++) {
                int q = t + 256 * p;
                int r = q >> 3;
                int c4 = (q & 7) * 4;
                float4 v = *reinterpret_cast<const float4*>(
                    &A[((size_t)g * LN + l0 + r) * K + k0 + c4]);
                As[r][c4 + 0] = v.x; As[r][c4 + 1] = v.y;
                As[r][c4 + 2] = v.z; As[r][c4 + 3] = v.w;
            }
        }
#pragma unroll
        for (int p = 0; p < 4; p++) {
            int q = t + 256 * p;
            int kk = q >> 5;
            int c4 = (q & 31) * 4;
            *reinterpret_cast<float4*>(&Bs[kk][c4]) =
                *reinterpret_cast<const float4*>(&W[(size_t)(k0 + kk) * CH + c4]);
        }
        __syncthreads();
#pragma unroll
        for (int kk = 0; kk < 32; kk++) {
            float a[4], b[8];
#pragma unroll
            for (int i = 0; i < 4; i++) a[i] = As[rg * 4 + i][kk];
#pragma unroll
            for (int j = 0; j < 8; j++) b[j] = Bs[kk][cg * 8 + j];
#pragma unroll
            for (int i = 0; i < 4; i++)
#pragma unroll
                for (int j = 0; j < 8; j++) acc[i][j] += a[i] * b[j];
        }
        __syncthreads();
    }
#pragma unroll
    for (int i = 0; i < 4; i++) {
        size_t row = (size_t)g * LN + l0 + rg * 4 + i;
        float4 v0 = make_float4(acc[i][0], acc[i][1], acc[i][2], acc[i][3]);
        float4 v1 = make_float4(acc[i][4], acc[i][5], acc[i][6], acc[i][7]);
        *reinterpret_cast<float4*>(&out[row * CH + cg * 8 + 0]) = v0;
        *reinterpret_cast<float4*>(&out[row * CH + cg * 8 + 4]) = v1;
    }
}

// ---------- CSR gather aggregation: a = sum_in norm*hw[src] + selfc*hw + bias ----------
__global__ __launch_bounds__(128) void k_gather(const float* __restrict__ hw,
                                                float* __restrict__ a,
                                                const int* __restrict__ off,
                                                const int* __restrict__ ssrc,
                                                const float* __restrict__ snorm,
                                                const float* __restrict__ selfc,
                                                const float* __restrict__ bias) {
    int l = blockIdx.x, g = blockIdx.y, c = threadIdx.x;
    const float* base = hw + (size_t)g * LN * CH;
    float acc = selfc[l] * base[(size_t)l * CH + c] + bias[c];
    int s0 = off[l], s1 = off[l + 1];
    for (int i = s0; i < s1; i++) {
        acc += snorm[i] * base[(size_t)ssrc[i] * CH + c];
    }
    a[((size_t)g * LN + l) * CH + c] = acc;
}

// ---------- mean over the N=16 sets within each batch ----------
__global__ __launch_bounds__(128) void k_nmean(const float* __restrict__ a,
                                               float* __restrict__ nm) {
    int l = blockIdx.x, b = blockIdx.y, c = threadIdx.x;
    float s = 0.f;
#pragma unroll
    for (int n = 0; n < NS; n++)
        s += a[(((size_t)(b * NS + n)) * LN + l) * CH + c];
    nm[((size_t)b * LN + l) * CH + c] = s * (1.0f / NS);
}

// ---------- per-channel variance of centered values (mean is exactly 0) ----------
__global__ __launch_bounds__(128) void k_var(const float* __restrict__ a,
                                             const float* __restrict__ nm,
                                             float* __restrict__ var) {
    int c = threadIdx.x;
    float part = 0.f;
    for (int row = blockIdx.x; row < GG * LN; row += gridDim.x) {
        int g = row >> 11;
        int l = row & (LN - 1);
        int b = g >> 4;
        float z = a[(size_t)row * CH + c] - nm[((size_t)b * LN + l) * CH + c];
        part += z * z;
    }
    atomicAdd(&var[c], part);
}

__global__ void k_scale(const float* __restrict__ var, const float* __restrict__ gam,
                        float* __restrict__ scale) {
    int c = threadIdx.x;
    scale[c] = gam[c] * rsqrtf(var[c] * (1.0f / (GG * LN)) + EPSV);
}

// ---------- mid-layer epilogue: h = relu((a - nm)*scale + beta), [G,L,C] ----------
__global__ __launch_bounds__(256) void k_epi(const float* __restrict__ a,
                                             const float* __restrict__ nm,
                                             const float* __restrict__ scale,
                                             const float* __restrict__ beta,
                                             float* __restrict__ h) {
    size_t total = (size_t)GG * LN * CH;
    for (size_t idx = (size_t)blockIdx.x * blockDim.x + threadIdx.x; idx < total;
         idx += (size_t)gridDim.x * blockDim.x) {
        int c = (int)(idx & (CH - 1));
        size_t row = idx >> 7;
        int l = (int)(row & (LN - 1));
        int g = (int)(row >> 11);
        int b = g >> 4;
        float z = (a[idx] - nm[((size_t)b * LN + l) * CH + c]) * scale[c] + beta[c];
        h[idx] = fmaxf(z, 0.f);
    }
}

// ---------- final epilogue with transpose to [G, C, L] ----------
__global__ __launch_bounds__(256) void k_epi_t(const float* __restrict__ a,
                                               const float* __restrict__ nm,
                                               const float* __restrict__ scale,
                                               const float* __restrict__ beta,
                                               float* __restrict__ out) {
    __shared__ float tbuf[32][33];
    int g = blockIdx.z;
    int c0 = blockIdx.y * 32;
    int l0 = blockIdx.x * 32;
    int tx = threadIdx.x, ty = threadIdx.y;
    int b = g >> 4;
#pragma unroll
    for (int k = 0; k < 4; k++) {
        int l = l0 + ty + 8 * k;
        int c = c0 + tx;
        float z = (a[((size_t)g * LN + l) * CH + c] - nm[((size_t)b * LN + l) * CH + c]) *
                      scale[c] + beta[c];
        tbuf[tx][ty + 8 * k] = fmaxf(z, 0.f);
    }
    __syncthreads();
#pragma unroll
    for (int k = 0; k < 4; k++) {
        int c = c0 + ty + 8 * k;
        out[((size_t)g * CH + c) * LN + l0 + tx] = tbuf[ty + 8 * k][tx];
    }
}

extern "C" void kernel_launch(void* const* d_in, const int* in_sizes, int n_in,
                              void* d_out, int out_size, void* d_ws, size_t ws_size,
                              hipStream_t stream) {
    const float* x   = (const float*)d_in[0];
    const int*   ei  = (const int*)d_in[1];
    const float* W1  = (const float*)d_in[2];
    const float* b1  = (const float*)d_in[3];
    const float* g1  = (const float*)d_in[4];
    const float* be1 = (const float*)d_in[5];
    const float* W2  = (const float*)d_in[6];
    const float* b2  = (const float*)d_in[7];
    const float* g2  = (const float*)d_in[8];
    const float* be2 = (const float*)d_in[9];
    const float* W3  = (const float*)d_in[10];
    const float* b3  = (const float*)d_in[11];
    const float* g3  = (const float*)d_in[12];
    const float* be3 = (const float*)d_in[13];
    const int* srcp = ei;
    const int* dstp = ei + EE;

    char* ws = (char*)d_ws;
    size_t pos = 0;
    auto alloc = [&](size_t bytes) -> void* {
        void* p = ws + pos;
        pos = (pos + bytes + 255) & ~(size_t)255;
        return p;
    };
    const size_t big = (size_t)GG * LN * CH * sizeof(float);  // 67.1 MB
    float* bufA  = (float*)alloc(big);
    float* nm    = (float*)alloc((size_t)BB * LN * CH * sizeof(float));
    int*   cnt   = (int*)alloc(LN * 4);
    int*   offA  = (int*)alloc((LN + 1) * 4);
    int*   cur   = (int*)alloc(LN * 4);
    float* dinv  = (float*)alloc(LN * 4);
    float* selfc = (float*)alloc(LN * 4);
    int*   ssrc  = (int*)alloc(EE * 4);
    float* snorm = (float*)alloc(EE * 4);
    float* var   = (float*)alloc(CH * 4);
    float* scl   = (float*)alloc(CH * 4);
    size_t needB = pos + big;
    bool planA = (ws_size >= needB);
    float* bufB = planA ? (float*)alloc(big) : (float*)d_out;

    // graph preprocessing (deterministic counts; fill order immaterial to tolerance)
    hipMemsetAsync(cnt, 0, LN * 4, stream);
    hipMemsetAsync(cur, 0, LN * 4, stream);
    k_deg<<<EE / 256, 256, 0, stream>>>(dstp, cnt);
    k_node<<<LN / 256, 256, 0, stream>>>(cnt, dinv, selfc);
    k_scan<<<1, 256, 0, stream>>>(cnt, offA);
    k_fill<<<EE / 256, 256, 0, stream>>>(srcp, dstp, offA, cur, dinv, ssrc, snorm);

    dim3 mmGrid(LN / 64, GG);
    dim3 gaGrid(LN, GG);
    dim3 nmGrid(LN, BB);

    // ---- layer 1: mm x->A ; gather A->B ; epi B->A ----
    k_mm<C_0, true><<<mmGrid, 256, 0, stream>>>(x, W1, bufA);
    k_gather<<<gaGrid, 128, 0, stream>>>(bufA, bufB, offA, ssrc, snorm, selfc, b1);
    k_nmean<<<nmGrid, 128, 0, stream>>>(bufB, nm);
    hipMemsetAsync(var, 0, CH * 4, stream);
    k_var<<<512, 128, 0, stream>>>(bufB, nm, var);
    k_scale<<<1, CH, 0, stream>>>(var, g1, scl);
    k_epi<<<4096, 256, 0, stream>>>(bufB, nm, scl, be1, bufA);

    // ---- layer 2: mm A->B ; gather B->A ; epi A->B ----
    k_mm<CH, false><<<mmGrid, 256, 0, stream>>>(bufA, W2, bufB);
    k_gather<<<gaGrid, 128, 0, stream>>>(bufB, bufA, offA, ssrc, snorm, selfc, b2);
    k_nmean<<<nmGrid, 128, 0, stream>>>(bufA, nm);
    hipMemsetAsync(var, 0, CH * 4, stream);
    k_var<<<512, 128, 0, stream>>>(bufA, nm, var);
    k_scale<<<1, CH, 0, stream>>>(var, g2, scl);
    k_epi<<<4096, 256, 0, stream>>>(bufA, nm, scl, be2, bufB);

    // ---- layer 3: mm B->A ; gather A->B ; final epi (transpose) ----
    k_mm<CH, false><<<mmGrid, 256, 0, stream>>>(bufB, W3, bufA);
    k_gather<<<gaGrid, 128, 0, stream>>>(bufA, bufB, offA, ssrc, snorm, selfc, b3);
    k_nmean<<<nmGrid, 128, 0, stream>>>(bufB, nm);
    hipMemsetAsync(var, 0, CH * 4, stream);
    k_var<<<512, 128, 0, stream>>>(bufB, nm, var);
    k_scale<<<1, CH, 0, stream>>>(var, g3, scl);

    dim3 teGrid(LN / 32, CH / 32, GG);
    dim3 teBlk(32, 8);
    if (planA) {
        k_epi_t<<<teGrid, teBlk, 0, stream>>>(bufB, nm, scl, be3, (float*)d_out);
    } else {
        // bufB == d_out: write transposed result to bufA, then d2d copy (capture-safe)
        k_epi_t<<<teGrid, teBlk, 0, stream>>>(bufB, nm, scl, be3, bufA);
        hipMemcpyAsync(d_out, bufA, big, hipMemcpyDeviceToDevice, stream);
    }
}

// Round 2
// 375.887 us; speedup vs baseline: 2.2976x; 2.2976x over previous
//
#include <hip/hip_runtime.h>
#include <hip/hip_bf16.h>

#define GG 64      // B*N graphs
#define LN 2048    // nodes per graph
#define BB 4       // batch
#define NS 16      // sets per batch
#define EE 16384   // edges
#define C_0 64
#define CH 128
#define EPSV 1e-5f
#define RS (GG * CH)   // 8192: row stride of [l][g][c]

using bf16x8 = __attribute__((ext_vector_type(8))) short;
using f32x4  = __attribute__((ext_vector_type(4))) float;

__device__ __forceinline__ float b2f(unsigned short u) {
    union { unsigned int i; float f; } v; v.i = ((unsigned int)u) << 16; return v.f;
}
__device__ __forceinline__ unsigned short f2b(float f) {
    union { float f; unsigned int i; } v; v.f = f;
    unsigned int r = v.i + 0x7fffu + ((v.i >> 16) & 1u);   // RNE
    return (unsigned short)(r >> 16);
}

// ---------- graph preprocessing ----------
__global__ void k_deg(const int* __restrict__ dst, int* __restrict__ cnt) {
    int e = blockIdx.x * blockDim.x + threadIdx.x;
    if (e < EE) atomicAdd(&cnt[dst[e]], 1);
}

__global__ void k_node(const int* __restrict__ cnt, float* __restrict__ dinv,
                       float* __restrict__ selfc) {
    int l = blockIdx.x * blockDim.x + threadIdx.x;
    if (l < LN) {
        float d = (float)cnt[l] + 2.0f;   // improved GCN: A + 2I
        float di = rsqrtf(d);
        dinv[l] = di;
        selfc[l] = 2.0f * di * di;
    }
}

__global__ void k_scan(const int* __restrict__ cnt, int* __restrict__ off) {
    __shared__ int part[256];
    __shared__ int pre[256];
    int t = threadIdx.x;
    int base = t * 8;
    int loc[8];
    int s = 0;
#pragma unroll
    for (int i = 0; i < 8; i++) { loc[i] = cnt[base + i]; s += loc[i]; }
    part[t] = s;
    __syncthreads();
    if (t == 0) {
        int run = 0;
        for (int i = 0; i < 256; i++) { pre[i] = run; run += part[i]; }
        off[LN] = run;
    }
    __syncthreads();
    int run = pre[t];
#pragma unroll
    for (int i = 0; i < 8; i++) { off[base + i] = run; run += loc[i]; }
}

__global__ void k_fill(const int* __restrict__ src, const int* __restrict__ dst,
                       const int* __restrict__ off, int* __restrict__ cur,
                       const float* __restrict__ dinv,
                       int* __restrict__ ssrc, float* __restrict__ snorm) {
    int e = blockIdx.x * blockDim.x + threadIdx.x;
    if (e < EE) {
        int s = src[e], d = dst[e];
        int pos = atomicAdd(&cur[d], 1);
        int idx = off[d] + pos;
        ssrc[idx] = s;
        snorm[idx] = dinv[s] * dinv[d];
    }
}

// ---------- W -> W^T bf16 ----------
__global__ void k_wprep(const float* __restrict__ W, unsigned short* __restrict__ Wt,
                        int K) {
    int idx = blockIdx.x * 256 + threadIdx.x;
    if (idx < K * CH) {
        int k = idx >> 7, c = idx & (CH - 1);
        Wt[c * K + k] = f2b(W[idx]);
    }
}

// ---------- MFMA GEMM: hw[l][g][co] = sum_k A[l][k] * W[k][co] (bf16, fp32 acc) ----------
// FUSE=false: layer 1, A comes from x fp32 [g][K][LN] (transposed staging).
// FUSE=true : A = relu((a_prev - nm) * scl + bet) staged from bf16 a_prev.
template <int K, bool FUSE>
__global__ __launch_bounds__(256) void k_mm(
    const float* __restrict__ X, const unsigned short* __restrict__ Ap,
    const float* __restrict__ nm, const float* __restrict__ scl,
    const float* __restrict__ bet, const unsigned short* __restrict__ Wt,
    unsigned short* __restrict__ hw)
{
    constexpr int KP = K + 8;                 // LDS k-pad (16B-aligned rows)
    __shared__ unsigned short As[64 * KP];
    __shared__ unsigned short Ws[128 * KP];
    const int g = blockIdx.y;
    const int l0 = blockIdx.x * 64;
    const int t = threadIdx.x;
    const int wq = t >> 6;
    const int lane = t & 63;

    // stage W^T tile (c-major, k contiguous)
    {
        const int c = t >> 1;
        const int kq = (t & 1) * (K / 2);
        const unsigned short* wp = Wt + c * K + kq;
        unsigned short* wd = Ws + c * KP + kq;
#pragma unroll
        for (int i = 0; i < K / 2; i += 8)
            *(uint4*)&wd[i] = *(const uint4*)&wp[i];
    }
    if (!FUSE) {
        // x fp32 [g][K][LN] -> As[l][k] bf16 (transpose in LDS)
        const int k = t >> 2;
        const int lq = (t & 3) * 16;
        const float* xp = X + ((size_t)g * K + k) * LN + l0 + lq;
#pragma unroll
        for (int i = 0; i < 16; i += 4) {
            float4 v = *(const float4*)&xp[i];
            As[(lq + i + 0) * KP + k] = f2b(v.x);
            As[(lq + i + 1) * KP + k] = f2b(v.y);
            As[(lq + i + 2) * KP + k] = f2b(v.z);
            As[(lq + i + 3) * KP + k] = f2b(v.w);
        }
    } else {
        // fused previous-layer epilogue during staging
        const int l = t >> 2;
        const int kq = (t & 3) * 32;
        const int lg = l0 + l;
        const int b = g >> 4;
        const unsigned short* ap = Ap + ((size_t)lg * GG + g) * CH + kq;
        const float* np = nm + ((size_t)lg * BB + b) * CH + kq;
        unsigned short* ad = As + l * KP + kq;
#pragma unroll
        for (int i = 0; i < 32; i += 8) {
            union { uint4 v; unsigned short s[8]; } u;
            u.v = *(const uint4*)&ap[i];
            float4 n0 = *(const float4*)&np[i];
            float4 n1 = *(const float4*)&np[i + 4];
            float4 s0 = *(const float4*)&scl[kq + i];
            float4 s1 = *(const float4*)&scl[kq + i + 4];
            float4 c0 = *(const float4*)&bet[kq + i];
            float4 c1 = *(const float4*)&bet[kq + i + 4];
            float z[8];
            z[0] = fmaxf((b2f(u.s[0]) - n0.x) * s0.x + c0.x, 0.f);
            z[1] = fmaxf((b2f(u.s[1]) - n0.y) * s0.y + c0.y, 0.f);
            z[2] = fmaxf((b2f(u.s[2]) - n0.z) * s0.z + c0.z, 0.f);
            z[3] = fmaxf((b2f(u.s[3]) - n0.w) * s0.w + c0.w, 0.f);
            z[4] = fmaxf((b2f(u.s[4]) - n1.x) * s1.x + c1.x, 0.f);
            z[5] = fmaxf((b2f(u.s[5]) - n1.y) * s1.y + c1.y, 0.f);
            z[6] = fmaxf((b2f(u.s[6]) - n1.z) * s1.z + c1.z, 0.f);
            z[7] = fmaxf((b2f(u.s[7]) - n1.w) * s1.w + c1.w, 0.f);
            union { uint4 v; unsigned short s[8]; } o;
#pragma unroll
            for (int j = 0; j < 8; j++) o.s[j] = f2b(z[j]);
            *(uint4*)&ad[i] = o.v;
        }
    }
    __syncthreads();

    f32x4 acc[8];
#pragma unroll
    for (int i = 0; i < 8; i++) acc[i] = (f32x4){0.f, 0.f, 0.f, 0.f};
    const int lr = lane & 15;
    const int kof = (lane >> 4) * 8;
#pragma unroll
    for (int ks = 0; ks < K / 32; ks++) {
        bf16x8 aF = *(const bf16x8*)&As[(wq * 16 + lr) * KP + ks * 32 + kof];
#pragma unroll
        for (int nf = 0; nf < 8; nf++) {
            bf16x8 bF = *(const bf16x8*)&Ws[(nf * 16 + lr) * KP + ks * 32 + kof];
            acc[nf] = __builtin_amdgcn_mfma_f32_16x16x32_bf16(aF, bF, acc[nf], 0, 0, 0);
        }
    }
    __syncthreads();
    // repack D (verified C/D map: col=lane&15, row=(lane>>4)*4+reg) -> LDS, then coalesced write
    unsigned short* Cs = Ws;   // reuse (128*KP >= 64*136 for K=64 and K=128)
#pragma unroll
    for (int nf = 0; nf < 8; nf++) {
#pragma unroll
        for (int r = 0; r < 4; r++) {
            int row = wq * 16 + (lane >> 4) * 4 + r;
            int col = nf * 16 + lr;
            Cs[row * 136 + col] = f2b(acc[nf][r]);
        }
    }
    __syncthreads();
    {
        const int l = t >> 2;
        const int cq = (t & 3) * 32;
        unsigned short* hp = hw + ((size_t)(l0 + l) * GG + g) * CH + cq;
#pragma unroll
        for (int i = 0; i < 32; i += 8)
            *(uint4*)&hp[i] = *(const uint4*)&Cs[l * 136 + cq + i];
    }
}

// ---------- fused gather + N-mean + variance ----------
// one block per destination node l; hw/a in [l][g][c] bf16; nm [l][b][c] fp32
__global__ __launch_bounds__(256) void k_gnv(
    const unsigned short* __restrict__ hw, unsigned short* __restrict__ a,
    float* __restrict__ nm, float* __restrict__ var,
    const int* __restrict__ off, const int* __restrict__ ssrc,
    const float* __restrict__ snorm, const float* __restrict__ selfc)
{
    __shared__ float lds[64 * 129];
    __shared__ float vpart[CH];
    const int l = blockIdx.x;
    const int t = threadIdx.x;
    const int g = t & 63;
    const int cq = (t >> 6) * 32;
    float acc[32];
    {
        const unsigned short* sp = hw + (size_t)l * RS + g * CH + cq;
        const float sc = selfc[l];
#pragma unroll
        for (int i = 0; i < 32; i += 8) {
            union { uint4 v; unsigned short s[8]; } u;
            u.v = *(const uint4*)&sp[i];
#pragma unroll
            for (int j = 0; j < 8; j++) acc[i + j] = sc * b2f(u.s[j]);
        }
    }
    const int s0 = off[l], s1 = off[l + 1];
    int e = s0;
    for (; e + 2 <= s1; e += 2) {                 // 2-deep for MLP
        int sA = ssrc[e], sB = ssrc[e + 1];
        float wA = snorm[e], wB = snorm[e + 1];
        const unsigned short* pA = hw + (size_t)sA * RS + g * CH + cq;
        const unsigned short* pB = hw + (size_t)sB * RS + g * CH + cq;
#pragma unroll
        for (int i = 0; i < 32; i += 8) {
            union { uint4 v; unsigned short s[8]; } uA, uB;
            uA.v = *(const uint4*)&pA[i];
            uB.v = *(const uint4*)&pB[i];
#pragma unroll
            for (int j = 0; j < 8; j++)
                acc[i + j] += wA * b2f(uA.s[j]) + wB * b2f(uB.s[j]);
        }
    }
    if (e < s1) {
        int sA = ssrc[e];
        float wA = snorm[e];
        const unsigned short* pA = hw + (size_t)sA * RS + g * CH + cq;
#pragma unroll
        for (int i = 0; i < 32; i += 8) {
            union { uint4 v; unsigned short s[8]; } uA;
            uA.v = *(const uint4*)&pA[i];
#pragma unroll
            for (int j = 0; j < 8; j++) acc[i + j] += wA * b2f(uA.s[j]);
        }
    }
    if (t < CH) vpart[t] = 0.f;
    {
        unsigned short* apd = a + (size_t)l * RS + g * CH + cq;
#pragma unroll
        for (int i = 0; i < 32; i += 8) {
            union { uint4 v; unsigned short s[8]; } o;
#pragma unroll
            for (int j = 0; j < 8; j++) o.s[j] = f2b(acc[i + j]);
            *(uint4*)&apd[i] = o.v;
        }
        float* lp = lds + g * 129 + cq;
#pragma unroll
        for (int i = 0; i < 32; i++) lp[i] = acc[i];
    }
    __syncthreads();
#pragma unroll
    for (int j = 0; j < 2; j++) {
        int idx = t + 256 * j;
        int b = idx >> 7, c = idx & (CH - 1);
        float s = 0.f;
#pragma unroll
        for (int n = 0; n < NS; n++) s += lds[(b * NS + n) * 129 + c];
        float m = s * (1.f / NS);
        nm[((size_t)l * BB + b) * CH + c] = m;
        float v = 0.f;
#pragma unroll
        for (int n = 0; n < NS; n++) {
            float d = lds[(b * NS + n) * 129 + c] - m;
            v += d * d;
        }
        atomicAdd(&vpart[c], v);
    }
    __syncthreads();
    if (t < CH) atomicAdd(&var[t], vpart[t]);
}

__global__ void k_scale(const float* __restrict__ var, const float* __restrict__ gam,
                        float* __restrict__ scl) {
    int c = threadIdx.x;
    scl[c] = gam[c] * rsqrtf(var[c] * (1.f / (GG * LN)) + EPSV);
}

// ---------- final epilogue with transpose to [g][c][l] fp32 ----------
__global__ __launch_bounds__(256) void k_epi_t(
    const unsigned short* __restrict__ a, const float* __restrict__ nm,
    const float* __restrict__ scl, const float* __restrict__ bet,
    float* __restrict__ out)
{
    __shared__ float tb[64][33];
    const int g = blockIdx.z;
    const int c0 = blockIdx.y * 64;
    const int l0 = blockIdx.x * 32;
    const int tx = threadIdx.x, ty = threadIdx.y;
    const int b = g >> 4;
    const int c = c0 + tx * 2;
    const float s0 = scl[c], s1 = scl[c + 1];
    const float e0 = bet[c], e1 = bet[c + 1];
#pragma unroll
    for (int k = 0; k < 4; k++) {
        int l = l0 + ty + 8 * k;
        unsigned int v = *(const unsigned int*)&a[((size_t)l * GG + g) * CH + c];
        const float* np = &nm[((size_t)l * BB + b) * CH + c];
        float z0 = fmaxf((b2f((unsigned short)(v & 0xffffu)) - np[0]) * s0 + e0, 0.f);
        float z1 = fmaxf((b2f((unsigned short)(v >> 16)) - np[1]) * s1 + e1, 0.f);
        tb[tx * 2][ty + 8 * k] = z0;
        tb[tx * 2 + 1][ty + 8 * k] = z1;
    }
    __syncthreads();
#pragma unroll
    for (int k = 0; k < 8; k++) {
        int cc = ty + 8 * k;
        out[((size_t)g * CH + c0 + cc) * LN + l0 + tx] = tb[cc][tx];
    }
}

extern "C" void kernel_launch(void* const* d_in, const int* in_sizes, int n_in,
                              void* d_out, int out_size, void* d_ws, size_t ws_size,
                              hipStream_t stream) {
    const float* x   = (const float*)d_in[0];
    const int*   ei  = (const int*)d_in[1];
    const float* W1  = (const float*)d_in[2];
    const float* g1  = (const float*)d_in[4];
    const float* be1 = (const float*)d_in[5];
    const float* W2  = (const float*)d_in[6];
    const float* g2  = (const float*)d_in[8];
    const float* be2 = (const float*)d_in[9];
    const float* W3  = (const float*)d_in[10];
    const float* g3  = (const float*)d_in[12];
    const float* be3 = (const float*)d_in[13];
    const int* srcp = ei;
    const int* dstp = ei + EE;

    char* ws = (char*)d_ws;
    size_t pos = 0;
    auto alloc = [&](size_t bytes) -> void* {
        void* p = ws + pos;
        pos = (pos + bytes + 255) & ~(size_t)255;
        return p;
    };
    const size_t big = (size_t)LN * RS * sizeof(unsigned short);  // 33.55 MB
    unsigned short* aB  = (unsigned short*)alloc(big);
    float* nm    = (float*)alloc((size_t)LN * BB * CH * sizeof(float));  // 4.2 MB
    unsigned short* Wt1 = (unsigned short*)alloc(C_0 * CH * 2);
    unsigned short* Wt2 = (unsigned short*)alloc(CH * CH * 2);
    unsigned short* Wt3 = (unsigned short*)alloc(CH * CH * 2);
    int*   cnt   = (int*)alloc(LN * 4);
    int*   offA  = (int*)alloc((LN + 1) * 4);
    int*   cur   = (int*)alloc(LN * 4);
    float* dinv  = (float*)alloc(LN * 4);
    float* selfc = (float*)alloc(LN * 4);
    int*   ssrc  = (int*)alloc(EE * 4);
    float* snorm = (float*)alloc(EE * 4);
    float* var   = (float*)alloc(CH * 4);
    float* scl   = (float*)alloc(CH * 4);
    // hw buffer: in ws if it fits, else alias d_out (hw is dead before epi_t writes out)
    unsigned short* hw = (ws_size >= pos + big) ? (unsigned short*)alloc(big)
                                                : (unsigned short*)d_out;

    // graph preprocessing
    hipMemsetAsync(cnt, 0, LN * 4, stream);
    hipMemsetAsync(cur, 0, LN * 4, stream);
    k_deg<<<EE / 256, 256, 0, stream>>>(dstp, cnt);
    k_node<<<LN / 256, 256, 0, stream>>>(cnt, dinv, selfc);
    k_scan<<<1, 256, 0, stream>>>(cnt, offA);
    k_fill<<<EE / 256, 256, 0, stream>>>(srcp, dstp, offA, cur, dinv, ssrc, snorm);
    k_wprep<<<(C_0 * CH) / 256, 256, 0, stream>>>(W1, Wt1, C_0);
    k_wprep<<<(CH * CH) / 256, 256, 0, stream>>>(W2, Wt2, CH);
    k_wprep<<<(CH * CH) / 256, 256, 0, stream>>>(W3, Wt3, CH);

    dim3 mmG(LN / 64, GG);

    // ---- layer 1 ----
    k_mm<C_0, false><<<mmG, 256, 0, stream>>>(x, nullptr, nullptr, nullptr, nullptr,
                                              Wt1, hw);
    hipMemsetAsync(var, 0, CH * 4, stream);
    k_gnv<<<LN, 256, 0, stream>>>(hw, aB, nm, var, offA, ssrc, snorm, selfc);
    k_scale<<<1, CH, 0, stream>>>(var, g1, scl);

    // ---- layer 2 (layer-1 epilogue fused into staging) ----
    k_mm<CH, true><<<mmG, 256, 0, stream>>>(nullptr, aB, nm, scl, be1, Wt2, hw);
    hipMemsetAsync(var, 0, CH * 4, stream);
    k_gnv<<<LN, 256, 0, stream>>>(hw, aB, nm, var, offA, ssrc, snorm, selfc);
    k_scale<<<1, CH, 0, stream>>>(var, g2, scl);

    // ---- layer 3 ----
    k_mm<CH, true><<<mmG, 256, 0, stream>>>(nullptr, aB, nm, scl, be2, Wt3, hw);
    hipMemsetAsync(var, 0, CH * 4, stream);
    k_gnv<<<LN, 256, 0, stream>>>(hw, aB, nm, var, offA, ssrc, snorm, selfc);
    k_scale<<<1, CH, 0, stream>>>(var, g3, scl);

    // ---- output ----
    dim3 teG(LN / 32, CH / 64, GG);
    dim3 teB(32, 8);
    k_epi_t<<<teG, teB, 0, stream>>>(aB, nm, scl, be3, (float*)d_out);
}

// Round 3
// 298.639 us; speedup vs baseline: 2.8920x; 1.2587x over previous
//
#include <hip/hip_runtime.h>
#include <hip/hip_bf16.h>

#define GG 64      // B*N graphs
#define LN 2048    // nodes per graph
#define BB 4       // batch
#define NS 16      // sets per batch
#define EE 16384   // edges
#define C_0 64
#define CH 128
#define EPSV 1e-5f
#define RS (GG * CH)   // 8192: row stride of [l][g][c]
#define VK 16          // variance atomic spread copies

using bf16x8 = __attribute__((ext_vector_type(8))) short;
using f32x4  = __attribute__((ext_vector_type(4))) float;

__device__ __forceinline__ float b2f(unsigned short u) {
    union { unsigned int i; float f; } v; v.i = ((unsigned int)u) << 16; return v.f;
}
__device__ __forceinline__ unsigned short f2b(float f) {
    union { float f; unsigned int i; } v; v.f = f;
    unsigned int r = v.i + 0x7fffu + ((v.i >> 16) & 1u);   // RNE
    return (unsigned short)(r >> 16);
}

// ---------- graph preprocessing ----------
__global__ void k_deg(const int* __restrict__ dst, int* __restrict__ cnt) {
    int e = blockIdx.x * blockDim.x + threadIdx.x;
    if (e < EE) atomicAdd(&cnt[dst[e]], 1);
}

__global__ void k_node(const int* __restrict__ cnt, float* __restrict__ dinv,
                       float* __restrict__ selfc) {
    int l = blockIdx.x * blockDim.x + threadIdx.x;
    if (l < LN) {
        float d = (float)cnt[l] + 2.0f;   // improved GCN: A + 2I
        float di = rsqrtf(d);
        dinv[l] = di;
        selfc[l] = 2.0f * di * di;
    }
}

__global__ void k_scan(const int* __restrict__ cnt, int* __restrict__ off) {
    __shared__ int part[256];
    __shared__ int pre[256];
    int t = threadIdx.x;
    int base = t * 8;
    int loc[8];
    int s = 0;
#pragma unroll
    for (int i = 0; i < 8; i++) { loc[i] = cnt[base + i]; s += loc[i]; }
    part[t] = s;
    __syncthreads();
    if (t == 0) {
        int run = 0;
        for (int i = 0; i < 256; i++) { pre[i] = run; run += part[i]; }
        off[LN] = run;
    }
    __syncthreads();
    int run = pre[t];
#pragma unroll
    for (int i = 0; i < 8; i++) { off[base + i] = run; run += loc[i]; }
}

__global__ void k_fill(const int* __restrict__ src, const int* __restrict__ dst,
                       const int* __restrict__ off, int* __restrict__ cur,
                       const float* __restrict__ dinv,
                       int* __restrict__ ssrc, float* __restrict__ snorm) {
    int e = blockIdx.x * blockDim.x + threadIdx.x;
    if (e < EE) {
        int s = src[e], d = dst[e];
        int pos = atomicAdd(&cur[d], 1);
        int idx = off[d] + pos;
        ssrc[idx] = s;
        snorm[idx] = dinv[s] * dinv[d];
    }
}

// ---------- W -> W^T bf16 ----------
__global__ void k_wprep(const float* __restrict__ W, unsigned short* __restrict__ Wt,
                        int K) {
    int idx = blockIdx.x * 256 + threadIdx.x;
    if (idx < K * CH) {
        int k = idx >> 7, c = idx & (CH - 1);
        Wt[c * K + k] = f2b(W[idx]);
    }
}

// ---------- MFMA GEMM: hw[l][g][co] = sum_k A[l][k] * W[k][co] (bf16, fp32 acc) ----------
template <int K, bool FUSE>
__global__ __launch_bounds__(256) void k_mm(
    const float* __restrict__ X, const unsigned short* __restrict__ Ap,
    const float* __restrict__ nm, const float* __restrict__ scl,
    const float* __restrict__ bet, const unsigned short* __restrict__ Wt,
    unsigned short* __restrict__ hw)
{
    constexpr int KP = K + 8;                 // LDS k-pad (16B-aligned rows)
    __shared__ unsigned short As[64 * KP];
    __shared__ unsigned short Ws[128 * KP];
    const int g = blockIdx.y;
    const int l0 = blockIdx.x * 64;
    const int t = threadIdx.x;
    const int wq = t >> 6;
    const int lane = t & 63;

    // stage W^T tile (c-major, k contiguous)
    {
        const int c = t >> 1;
        const int kq = (t & 1) * (K / 2);
        const unsigned short* wp = Wt + c * K + kq;
        unsigned short* wd = Ws + c * KP + kq;
#pragma unroll
        for (int i = 0; i < K / 2; i += 8)
            *(uint4*)&wd[i] = *(const uint4*)&wp[i];
    }
    if (!FUSE) {
        // x fp32 [g][K][LN] -> As[l][k] bf16 (transpose in LDS)
        const int k = t >> 2;
        const int lq = (t & 3) * 16;
        const float* xp = X + ((size_t)g * K + k) * LN + l0 + lq;
#pragma unroll
        for (int i = 0; i < 16; i += 4) {
            float4 v = *(const float4*)&xp[i];
            As[(lq + i + 0) * KP + k] = f2b(v.x);
            As[(lq + i + 1) * KP + k] = f2b(v.y);
            As[(lq + i + 2) * KP + k] = f2b(v.z);
            As[(lq + i + 3) * KP + k] = f2b(v.w);
        }
    } else {
        // fused previous-layer epilogue during staging
        const int l = t >> 2;
        const int kq = (t & 3) * 32;
        const int lg = l0 + l;
        const int b = g >> 4;
        const unsigned short* ap = Ap + ((size_t)lg * GG + g) * CH + kq;
        const float* np = nm + ((size_t)lg * BB + b) * CH + kq;
        unsigned short* ad = As + l * KP + kq;
#pragma unroll
        for (int i = 0; i < 32; i += 8) {
            union { uint4 v; unsigned short s[8]; } u;
            u.v = *(const uint4*)&ap[i];
            float4 n0 = *(const float4*)&np[i];
            float4 n1 = *(const float4*)&np[i + 4];
            float4 s0 = *(const float4*)&scl[kq + i];
            float4 s1 = *(const float4*)&scl[kq + i + 4];
            float4 c0 = *(const float4*)&bet[kq + i];
            float4 c1 = *(const float4*)&bet[kq + i + 4];
            float z[8];
            z[0] = fmaxf((b2f(u.s[0]) - n0.x) * s0.x + c0.x, 0.f);
            z[1] = fmaxf((b2f(u.s[1]) - n0.y) * s0.y + c0.y, 0.f);
            z[2] = fmaxf((b2f(u.s[2]) - n0.z) * s0.z + c0.z, 0.f);
            z[3] = fmaxf((b2f(u.s[3]) - n0.w) * s0.w + c0.w, 0.f);
            z[4] = fmaxf((b2f(u.s[4]) - n1.x) * s1.x + c1.x, 0.f);
            z[5] = fmaxf((b2f(u.s[5]) - n1.y) * s1.y + c1.y, 0.f);
            z[6] = fmaxf((b2f(u.s[6]) - n1.z) * s1.z + c1.z, 0.f);
            z[7] = fmaxf((b2f(u.s[7]) - n1.w) * s1.w + c1.w, 0.f);
            union { uint4 v; unsigned short s[8]; } o;
#pragma unroll
            for (int j = 0; j < 8; j++) o.s[j] = f2b(z[j]);
            *(uint4*)&ad[i] = o.v;
        }
    }
    __syncthreads();

    f32x4 acc[8];
#pragma unroll
    for (int i = 0; i < 8; i++) acc[i] = (f32x4){0.f, 0.f, 0.f, 0.f};
    const int lr = lane & 15;
    const int kof = (lane >> 4) * 8;
#pragma unroll
    for (int ks = 0; ks < K / 32; ks++) {
        bf16x8 aF = *(const bf16x8*)&As[(wq * 16 + lr) * KP + ks * 32 + kof];
#pragma unroll
        for (int nf = 0; nf < 8; nf++) {
            bf16x8 bF = *(const bf16x8*)&Ws[(nf * 16 + lr) * KP + ks * 32 + kof];
            acc[nf] = __builtin_amdgcn_mfma_f32_16x16x32_bf16(aF, bF, acc[nf], 0, 0, 0);
        }
    }
    __syncthreads();
    // repack D (C/D map: col=lane&15, row=(lane>>4)*4+reg) -> LDS, then coalesced write
    unsigned short* Cs = Ws;   // reuse
#pragma unroll
    for (int nf = 0; nf < 8; nf++) {
#pragma unroll
        for (int r = 0; r < 4; r++) {
            int row = wq * 16 + (lane >> 4) * 4 + r;
            int col = nf * 16 + lr;
            Cs[row * 136 + col] = f2b(acc[nf][r]);
        }
    }
    __syncthreads();
    {
        const int l = t >> 2;
        const int cq = (t & 3) * 32;
        unsigned short* hp = hw + ((size_t)(l0 + l) * GG + g) * CH + cq;
#pragma unroll
        for (int i = 0; i < 32; i += 8)
            *(uint4*)&hp[i] = *(const uint4*)&Cs[l * 136 + cq + i];
    }
}

// ---------- fused gather + N-mean + variance, 2 blocks per node (g-halves) ----------
// block bid: node l = bid>>1, graphs [32*(bid&1), 32*(bid&1)+32)
// thread t: local graph gl = t>>3, channels c0 = (t&7)*16 .. +16
__global__ __launch_bounds__(256) void k_gnv(
    const unsigned short* __restrict__ hw, unsigned short* __restrict__ a,
    float* __restrict__ nm, float* __restrict__ varK,
    const int* __restrict__ off, const int* __restrict__ ssrc,
    const float* __restrict__ snorm, const float* __restrict__ selfc)
{
    __shared__ unsigned short lds[32 * 136];   // 8.7 KB bf16 stash
    const int bid = blockIdx.x;
    const int l = bid >> 1;
    const int g0 = (bid & 1) * 32;
    const int t = threadIdx.x;
    const int gl = t >> 3;
    const int c0 = (t & 7) * 16;
    const size_t rowoff = (size_t)(g0 + gl) * CH + c0;

    float acc[16];
    {
        const unsigned short* sp = hw + (size_t)l * RS + rowoff;
        const float sc = selfc[l];
        union { uint4 v; unsigned short s[8]; } u0, u1;
        u0.v = *(const uint4*)&sp[0];
        u1.v = *(const uint4*)&sp[8];
#pragma unroll
        for (int j = 0; j < 8; j++) {
            acc[j] = sc * b2f(u0.s[j]);
            acc[8 + j] = sc * b2f(u1.s[j]);
        }
    }
    const int s0 = off[l], s1 = off[l + 1];
    int e = s0;
    for (; e + 4 <= s1; e += 4) {
        int sA = ssrc[e], sB = ssrc[e + 1], sC = ssrc[e + 2], sD = ssrc[e + 3];
        float wA = snorm[e], wB = snorm[e + 1], wC = snorm[e + 2], wD = snorm[e + 3];
        union { uint4 v; unsigned short s[8]; } uA0, uA1, uB0, uB1, uC0, uC1, uD0, uD1;
        const unsigned short* pA = hw + (size_t)sA * RS + rowoff;
        const unsigned short* pB = hw + (size_t)sB * RS + rowoff;
        const unsigned short* pC = hw + (size_t)sC * RS + rowoff;
        const unsigned short* pD = hw + (size_t)sD * RS + rowoff;
        uA0.v = *(const uint4*)&pA[0]; uA1.v = *(const uint4*)&pA[8];
        uB0.v = *(const uint4*)&pB[0]; uB1.v = *(const uint4*)&pB[8];
        uC0.v = *(const uint4*)&pC[0]; uC1.v = *(const uint4*)&pC[8];
        uD0.v = *(const uint4*)&pD[0]; uD1.v = *(const uint4*)&pD[8];
#pragma unroll
        for (int j = 0; j < 8; j++) {
            acc[j]     += wA * b2f(uA0.s[j]) + wB * b2f(uB0.s[j]) +
                          wC * b2f(uC0.s[j]) + wD * b2f(uD0.s[j]);
            acc[8 + j] += wA * b2f(uA1.s[j]) + wB * b2f(uB1.s[j]) +
                          wC * b2f(uC1.s[j]) + wD * b2f(uD1.s[j]);
        }
    }
    for (; e < s1; e++) {
        int sA = ssrc[e];
        float wA = snorm[e];
        const unsigned short* pA = hw + (size_t)sA * RS + rowoff;
        union { uint4 v; unsigned short s[8]; } uA0, uA1;
        uA0.v = *(const uint4*)&pA[0]; uA1.v = *(const uint4*)&pA[8];
#pragma unroll
        for (int j = 0; j < 8; j++) {
            acc[j] += wA * b2f(uA0.s[j]);
            acc[8 + j] += wA * b2f(uA1.s[j]);
        }
    }
    // pack once; store to aB and to LDS stash
    union { uint4 v; unsigned short s[8]; } o0, o1;
#pragma unroll
    for (int j = 0; j < 8; j++) { o0.s[j] = f2b(acc[j]); o1.s[j] = f2b(acc[8 + j]); }
    {
        unsigned short* apd = a + (size_t)l * RS + rowoff;
        *(uint4*)&apd[0] = o0.v;
        *(uint4*)&apd[8] = o1.v;
        unsigned short* lp = lds + gl * 136 + c0;
        *(uint4*)&lp[0] = o0.v;
        *(uint4*)&lp[8] = o1.v;
    }
    __syncthreads();
    // reduce: thread t -> local batch bl = t>>7 (2 batches of 16 graphs), channel c = t&127
    {
        const int bl = t >> 7;
        const int c = t & (CH - 1);
        float x[NS];
        float s = 0.f;
#pragma unroll
        for (int n = 0; n < NS; n++) {
            x[n] = b2f(lds[(bl * NS + n) * 136 + c]);
            s += x[n];
        }
        float m = s * (1.f / NS);
        nm[((size_t)l * BB + (g0 >> 4) + bl) * CH + c] = m;
        float v = 0.f;
#pragma unroll
        for (int n = 0; n < NS; n++) {
            float d = x[n] - m;
            v += d * d;
        }
        atomicAdd(&varK[(bid & (VK - 1)) * CH + c], v);
    }
}

__global__ void k_scale(const float* __restrict__ varK, const float* __restrict__ gam,
                        float* __restrict__ scl) {
    int c = threadIdx.x;
    float v = 0.f;
#pragma unroll
    for (int k = 0; k < VK; k++) v += varK[k * CH + c];
    scl[c] = gam[c] * rsqrtf(v * (1.f / (GG * LN)) + EPSV);
}

// ---------- final epilogue with transpose to [g][c][l] fp32 ----------
__global__ __launch_bounds__(256) void k_epi_t(
    const unsigned short* __restrict__ a, const float* __restrict__ nm,
    const float* __restrict__ scl, const float* __restrict__ bet,
    float* __restrict__ out)
{
    __shared__ float tb[64][33];
    const int g = blockIdx.z;
    const int c0 = blockIdx.y * 64;
    const int l0 = blockIdx.x * 32;
    const int tx = threadIdx.x, ty = threadIdx.y;
    const int b = g >> 4;
    const int c = c0 + tx * 2;
    const float s0 = scl[c], s1 = scl[c + 1];
    const float e0 = bet[c], e1 = bet[c + 1];
#pragma unroll
    for (int k = 0; k < 4; k++) {
        int l = l0 + ty + 8 * k;
        unsigned int v = *(const unsigned int*)&a[((size_t)l * GG + g) * CH + c];
        const float* np = &nm[((size_t)l * BB + b) * CH + c];
        float z0 = fmaxf((b2f((unsigned short)(v & 0xffffu)) - np[0]) * s0 + e0, 0.f);
        float z1 = fmaxf((b2f((unsigned short)(v >> 16)) - np[1]) * s1 + e1, 0.f);
        tb[tx * 2][ty + 8 * k] = z0;
        tb[tx * 2 + 1][ty + 8 * k] = z1;
    }
    __syncthreads();
#pragma unroll
    for (int k = 0; k < 8; k++) {
        int cc = ty + 8 * k;
        out[((size_t)g * CH + c0 + cc) * LN + l0 + tx] = tb[cc][tx];
    }
}

extern "C" void kernel_launch(void* const* d_in, const int* in_sizes, int n_in,
                              void* d_out, int out_size, void* d_ws, size_t ws_size,
                              hipStream_t stream) {
    const float* x   = (const float*)d_in[0];
    const int*   ei  = (const int*)d_in[1];
    const float* W1  = (const float*)d_in[2];
    const float* g1  = (const float*)d_in[4];
    const float* be1 = (const float*)d_in[5];
    const float* W2  = (const float*)d_in[6];
    const float* g2  = (const float*)d_in[8];
    const float* be2 = (const float*)d_in[9];
    const float* W3  = (const float*)d_in[10];
    const float* g3  = (const float*)d_in[12];
    const float* be3 = (const float*)d_in[13];
    const int* srcp = ei;
    const int* dstp = ei + EE;

    char* ws = (char*)d_ws;
    size_t pos = 0;
    auto alloc = [&](size_t bytes) -> void* {
        void* p = ws + pos;
        pos = (pos + bytes + 255) & ~(size_t)255;
        return p;
    };
    const size_t big = (size_t)LN * RS * sizeof(unsigned short);  // 33.55 MB
    unsigned short* aB  = (unsigned short*)alloc(big);
    float* nm    = (float*)alloc((size_t)LN * BB * CH * sizeof(float));  // 4.2 MB
    unsigned short* Wt1 = (unsigned short*)alloc(C_0 * CH * 2);
    unsigned short* Wt2 = (unsigned short*)alloc(CH * CH * 2);
    unsigned short* Wt3 = (unsigned short*)alloc(CH * CH * 2);
    int*   cnt   = (int*)alloc(LN * 4);
    int*   offA  = (int*)alloc((LN + 1) * 4);
    int*   cur   = (int*)alloc(LN * 4);
    float* dinv  = (float*)alloc(LN * 4);
    float* selfc = (float*)alloc(LN * 4);
    int*   ssrc  = (int*)alloc(EE * 4);
    float* snorm = (float*)alloc(EE * 4);
    float* varK  = (float*)alloc(VK * CH * 4);
    float* scl   = (float*)alloc(CH * 4);
    unsigned short* hw = (ws_size >= pos + big) ? (unsigned short*)alloc(big)
                                                : (unsigned short*)d_out;

    // graph preprocessing
    hipMemsetAsync(cnt, 0, LN * 4, stream);
    hipMemsetAsync(cur, 0, LN * 4, stream);
    k_deg<<<EE / 256, 256, 0, stream>>>(dstp, cnt);
    k_node<<<LN / 256, 256, 0, stream>>>(cnt, dinv, selfc);
    k_scan<<<1, 256, 0, stream>>>(cnt, offA);
    k_fill<<<EE / 256, 256, 0, stream>>>(srcp, dstp, offA, cur, dinv, ssrc, snorm);
    k_wprep<<<(C_0 * CH) / 256, 256, 0, stream>>>(W1, Wt1, C_0);
    k_wprep<<<(CH * CH) / 256, 256, 0, stream>>>(W2, Wt2, CH);
    k_wprep<<<(CH * CH) / 256, 256, 0, stream>>>(W3, Wt3, CH);

    dim3 mmG(LN / 64, GG);

    // ---- layer 1 ----
    k_mm<C_0, false><<<mmG, 256, 0, stream>>>(x, nullptr, nullptr, nullptr, nullptr,
                                              Wt1, hw);
    hipMemsetAsync(varK, 0, VK * CH * 4, stream);
    k_gnv<<<LN * 2, 256, 0, stream>>>(hw, aB, nm, varK, offA, ssrc, snorm, selfc);
    k_scale<<<1, CH, 0, stream>>>(varK, g1, scl);

    // ---- layer 2 (layer-1 epilogue fused into staging) ----
    k_mm<CH, true><<<mmG, 256, 0, stream>>>(nullptr, aB, nm, scl, be1, Wt2, hw);
    hipMemsetAsync(varK, 0, VK * CH * 4, stream);
    k_gnv<<<LN * 2, 256, 0, stream>>>(hw, aB, nm, varK, offA, ssrc, snorm, selfc);
    k_scale<<<1, CH, 0, stream>>>(varK, g2, scl);

    // ---- layer 3 ----
    k_mm<CH, true><<<mmG, 256, 0, stream>>>(nullptr, aB, nm, scl, be2, Wt3, hw);
    hipMemsetAsync(varK, 0, VK * CH * 4, stream);
    k_gnv<<<LN * 2, 256, 0, stream>>>(hw, aB, nm, varK, offA, ssrc, snorm, selfc);
    k_scale<<<1, CH, 0, stream>>>(varK, g3, scl);

    // ---- output ----
    dim3 teG(LN / 32, CH / 64, GG);
    dim3 teB(32, 8);
    k_epi_t<<<teG, teB, 0, stream>>>(aB, nm, scl, be3, (float*)d_out);
}